// Round 4
// baseline (1086.331 us; speedup 1.0000x reference)
//
#include <hip/hip_runtime.h>
#include <math.h>

// Problem constants
#define NB 16      // batch
#define NE 128     // experts / channels
#define NK 8
#define HW 16384   // 128*128
#define NPIX (NB * HW)

typedef float v2f __attribute__((ext_vector_type(2)));

// f32 transposed gate weights: gwT[e][f] = gate_w[f][e]
__device__ float g_gwT[NE * NE];

__global__ __launch_bounds__(256) void cvt_gw_kernel(const float* __restrict__ gate_w) {
    int i = blockIdx.x * 256 + threadIdx.x;   // i = e*128 + f
    if (i < NE * NE) {
        int e = i >> 7;
        int f = i & 127;
        g_gwT[i] = gate_w[f * NE + e];
    }
}

__global__ __launch_bounds__(256) void moe_kernel(const float* __restrict__ experts,
                                                  const float* __restrict__ gate_b,
                                                  float* __restrict__ out) {
    const int p  = blockIdx.x * 256 + threadIdx.x;   // pixel id
    const int n  = p >> 14;                          // /16384
    const int hw = p & (HW - 1);

    const float* xp = experts + ((size_t)n * NE * HW + hw);   // channel stride HW

    // acc as float2 pairs: acc[j] covers f = 2j, 2j+1. Each elementwise-fma half
    // is an exact IEEE f32 FMA -> bit-identical to the round-2 scalar fmaf chain.
    v2f acc[NE / 2];
#pragma unroll
    for (int j = 0; j < NE / 2; ++j) acc[j] = (v2f){0.0f, 0.0f};

    // ---- logits: chunked (8-channel) register double-buffered matvec ----
    // One e-step: acc[j] += gw[e][2j,2j+1] * x[e]
#define E_STEP(EIDX, XV)                                                 \
    {                                                                    \
        v2f xb2; xb2.x = (XV); xb2.y = (XV);                             \
        const v2f* g2 = (const v2f*)&g_gwT[(size_t)(EIDX) * NE];         \
        _Pragma("unroll")                                                \
        for (int j = 0; j < NE / 2; ++j) {                               \
            acc[j] = __builtin_elementwise_fma(g2[j], xb2, acc[j]);      \
        }                                                                \
    }

    float xa[8], xb[8];
    const float* xq = xp;                 // chunk base pointer, steps by 8*HW
#pragma unroll
    for (int i = 0; i < 8; ++i) xa[i] = xq[(size_t)i * HW];   // chunk 0

    for (int c = 0; c < 16; c += 2) {     // 16 chunks of 8 channels
        // prefetch chunk c+1 into xb (c+1 <= 15 always)
        const float* xq1 = xq + (size_t)8 * HW;
#pragma unroll
        for (int i = 0; i < 8; ++i) xb[i] = xq1[(size_t)i * HW];

        // compute chunk c from xa
#pragma unroll
        for (int i = 0; i < 8; ++i) { E_STEP(8 * c + i, xa[i]); }

        // prefetch chunk c+2 into xa (skip on last pair)
        if (c + 2 < 16) {
            const float* xq2 = xq + (size_t)16 * HW;
#pragma unroll
            for (int i = 0; i < 8; ++i) xa[i] = xq2[(size_t)i * HW];
        }

        // compute chunk c+1 from xb
#pragma unroll
        for (int i = 0; i < 8; ++i) { E_STEP(8 * (c + 1) + i, xb[i]); }

        xq += (size_t)16 * HW;
    }
#undef E_STEP

    // ---- + bias (after the chain, exactly as the passing round-2 version) ----
#pragma unroll
    for (int j = 0; j < NE / 2; ++j) {
        acc[j].x = acc[j].x + gate_b[2 * j];
        acc[j].y = acc[j].y + gate_b[2 * j + 1];
    }

    // ---- softmax, f32 numpy semantics (bit-frozen) ----
    float m = acc[0].x;
    m = fmaxf(m, acc[0].y);
#pragma unroll
    for (int j = 1; j < NE / 2; ++j) {
        m = fmaxf(m, acc[j].x);
        m = fmaxf(m, acc[j].y);
    }

    // correctly-rounded f32 exp of (l - m)
#pragma unroll
    for (int j = 0; j < NE / 2; ++j) {
        acc[j].x = (float)exp((double)(acc[j].x - m));
        acc[j].y = (float)exp((double)(acc[j].y - m));
    }

    // denominator: sequential ascending-f f32 sum
    float s = acc[0].x;
    s = s + acc[0].y;
#pragma unroll
    for (int j = 1; j < NE / 2; ++j) {
        s = s + acc[j].x;
        s = s + acc[j].y;
    }

    // routing weights: IEEE f32 divide (ranking happens in w space -> mirror it)
#pragma unroll
    for (int j = 0; j < NE / 2; ++j) {
        acc[j].x = acc[j].x / s;
        acc[j].y = acc[j].y / s;
    }

    // ---- top-8 on (w desc, idx asc): ascending-f insertion, strict '>' ----
    float t_v[NK];
    int   t_i[NK];
#pragma unroll
    for (int i = 0; i < NK; ++i) { t_v[i] = -1.0f; t_i[i] = 0; }

#pragma unroll
    for (int j = 0; j < NE / 2; ++j) {
#pragma unroll
        for (int h = 0; h < 2; ++h) {
            float v  = h ? acc[j].y : acc[j].x;
            int   ix = 2 * j + h;
#pragma unroll
            for (int i = 0; i < NK; ++i) {
                bool gt = v > t_v[i];
                float tv = t_v[i]; int ti = t_i[i];
                t_v[i] = gt ? v  : tv;
                t_i[i] = gt ? ix : ti;
                v      = gt ? tv : v;
                ix     = gt ? ti : ix;
            }
        }
    }

    // ---- gather + scale + write ----
    float* op = out + ((size_t)n * NK * HW + hw);
#pragma unroll
    for (int k = 0; k < NK; ++k) {
        float xv = xp[(size_t)t_i[k] * HW];
        op[(size_t)k * HW] = t_v[k] * xv;
    }
}

extern "C" void kernel_launch(void* const* d_in, const int* in_sizes, int n_in,
                              void* d_out, int out_size, void* d_ws, size_t ws_size,
                              hipStream_t stream) {
    // inputs: 0=x (unused), 1=experts [N,E,H,W] f32, 2=gate_w [E,E] f32, 3=gate_b [E] f32
    const float* experts = (const float*)d_in[1];
    const float* gate_w  = (const float*)d_in[2];
    const float* gate_b  = (const float*)d_in[3];
    float* out = (float*)d_out;

    hipLaunchKernelGGL(cvt_gw_kernel, dim3((NE * NE + 255) / 256), dim3(256), 0, stream, gate_w);
    hipLaunchKernelGGL(moe_kernel, dim3(NPIX / 256), dim3(256), 0, stream, experts, gate_b, out);
}

// Round 5
// 584.159 us; speedup vs baseline: 1.8596x; 1.8596x over previous
//
#include <hip/hip_runtime.h>
#include <math.h>

// Problem constants
#define NB 16      // batch
#define NE 128     // experts / channels
#define NK 8
#define HW 16384   // 128*128
#define NPIX (NB * HW)

#define CH 16      // channels staged per chunk
#define NCHUNK (NE / CH)   // 8

// f32 transposed gate weights: gwT[e][f] = gate_w[f][e]
__device__ float g_gwT[NE * NE];

__global__ __launch_bounds__(256) void cvt_gw_kernel(const float* __restrict__ gate_w) {
    int i = blockIdx.x * 256 + threadIdx.x;   // i = e*128 + f
    if (i < NE * NE) {
        int e = i >> 7;
        int f = i & 127;
        g_gwT[i] = gate_w[f * NE + e];
    }
}

__global__ __launch_bounds__(256) void moe_kernel(const float* __restrict__ experts,
                                                  const float* __restrict__ gate_b,
                                                  float* __restrict__ out) {
    const int tid = threadIdx.x;
    const int wv  = tid >> 6;                        // wave id in block
    const int p   = blockIdx.x * 256 + tid;          // pixel id
    const int n   = p >> 14;                         // /16384
    const int hw  = p & (HW - 1);

    const float* xp    = experts + ((size_t)n * NE * HW + hw);          // per-thread column
    const float* xbase = experts + ((size_t)n * NE * HW + ((size_t)blockIdx.x * 256 & (HW - 1)));

    // double-buffered x staging: xs[buf][chan_in_chunk][pixel_in_block]
    __shared__ float xs[2][CH][256];

    // stage chunk c into buffer b: wave wv covers pixels [64*wv, 64*wv+63] for
    // each of the CH channels. LDS dest = uniform base + lane*4 (linear), global
    // src is per-lane -> exactly the global_load_lds contract.
#define STAGE(c, b)                                                                   \
    {                                                                                 \
        const float* gsrc = xbase + (size_t)(c) * CH * HW;                            \
        _Pragma("unroll")                                                             \
        for (int i = 0; i < CH; ++i) {                                                \
            __builtin_amdgcn_global_load_lds(                                         \
                (const __attribute__((address_space(1))) void*)(gsrc + (size_t)i * HW + tid), \
                (__attribute__((address_space(3))) void*)&xs[b][i][wv * 64],          \
                4, 0, 0);                                                             \
        }                                                                             \
    }

    float acc[NE];
#pragma unroll
    for (int f = 0; f < NE; ++f) acc[f] = 0.0f;

    STAGE(0, 0);
    __syncthreads();   // vmcnt(0) drain + barrier: buf0 ready

    for (int c = 0; c < NCHUNK; ++c) {
        const int cur = c & 1;
        if (c + 1 < NCHUNK) STAGE(c + 1, cur ^ 1);   // issue prefetch before compute

        // ---- compute chunk c: identical fmaf chain as the passing round-2 code ----
#pragma unroll
        for (int i = 0; i < CH; ++i) {
            float xe = xs[cur][i][tid];
            const float* gw = &g_gwT[(size_t)(c * CH + i) * NE];   // wave-uniform -> s_load
#pragma unroll
            for (int f = 0; f < NE; ++f) {
                acc[f] = fmaf(gw[f], xe, acc[f]);
            }
        }
        __syncthreads();   // drains prefetch (already landed) + publishes next buffer
    }
#undef STAGE

    // ---- + bias (zeros here; mirrored for fidelity) ----
#pragma unroll
    for (int f = 0; f < NE; ++f) acc[f] = acc[f] + gate_b[f];

    // ---- softmax, f32 numpy semantics (bit-frozen from the passing version) ----
    float m = acc[0];
#pragma unroll
    for (int f = 1; f < NE; ++f) m = fmaxf(m, acc[f]);

    // correctly-rounded f32 exp of (l - m)
#pragma unroll
    for (int f = 0; f < NE; ++f) {
        acc[f] = (float)exp((double)(acc[f] - m));
    }

    // denominator: sequential ascending f32 sum (np strided-axis reduce order)
    float s = acc[0];
#pragma unroll
    for (int f = 1; f < NE; ++f) s = s + acc[f];

    // routing weights: IEEE f32 divide (ranking happens in w space -> mirror it)
#pragma unroll
    for (int f = 0; f < NE; ++f) acc[f] = acc[f] / s;

    // ---- top-8 on (w desc, idx asc): ascending-f insertion, strict '>' ----
    float t_v[NK];
    int   t_i[NK];
#pragma unroll
    for (int i = 0; i < NK; ++i) { t_v[i] = -1.0f; t_i[i] = 0; }

#pragma unroll
    for (int f = 0; f < NE; ++f) {
        float v  = acc[f];
        int   ix = f;
#pragma unroll
        for (int i = 0; i < NK; ++i) {
            bool gt = v > t_v[i];
            float tv = t_v[i]; int ti = t_i[i];
            t_v[i] = gt ? v  : tv;
            t_i[i] = gt ? ix : ti;
            v      = gt ? tv : v;
            ix     = gt ? ti : ix;
        }
    }

    // ---- gather + scale + write ----
    float* op = out + ((size_t)n * NK * HW + hw);
#pragma unroll
    for (int k = 0; k < NK; ++k) {
        float xv = xp[(size_t)t_i[k] * HW];
        op[(size_t)k * HW] = t_v[k] * xv;
    }
}

extern "C" void kernel_launch(void* const* d_in, const int* in_sizes, int n_in,
                              void* d_out, int out_size, void* d_ws, size_t ws_size,
                              hipStream_t stream) {
    // inputs: 0=x (unused), 1=experts [N,E,H,W] f32, 2=gate_w [E,E] f32, 3=gate_b [E] f32
    const float* experts = (const float*)d_in[1];
    const float* gate_w  = (const float*)d_in[2];
    const float* gate_b  = (const float*)d_in[3];
    float* out = (float*)d_out;

    hipLaunchKernelGGL(cvt_gw_kernel, dim3((NE * NE + 255) / 256), dim3(256), 0, stream, gate_w);
    hipLaunchKernelGGL(moe_kernel, dim3(NPIX / 256), dim3(256), 0, stream, experts, gate_b, out);
}

// Round 6
// 394.587 us; speedup vs baseline: 2.7531x; 1.4804x over previous
//
#include <hip/hip_runtime.h>
#include <math.h>

// Problem constants
#define NB 16      // batch
#define NE 128     // experts / channels
#define NK 8
#define HW 16384   // 128*128
#define NPIX (NB * HW)

// f32 transposed gate weights: gwT[e][f] = gate_w[f][e]
__device__ float g_gwT[NE * NE];

__global__ __launch_bounds__(256) void cvt_gw_kernel(const float* __restrict__ gate_w) {
    int i = blockIdx.x * 256 + threadIdx.x;   // i = e*128 + f
    if (i < NE * NE) {
        int e = i >> 7;
        int f = i & 127;
        g_gwT[i] = gate_w[f * NE + e];
    }
}

__global__ __launch_bounds__(256) void moe_kernel(const float* __restrict__ experts,
                                                  const float* __restrict__ gate_b,
                                                  float* __restrict__ out) {
    const int tid = threadIdx.x;
    const int p   = blockIdx.x * 256 + tid;          // pixel id
    const int n   = p >> 14;                         // /16384
    const int hw  = p & (HW - 1);

    const float* xp = experts + ((size_t)n * NE * HW + hw);   // channel stride HW

    // ---- one-time stage: gwT (64 KB) into LDS, bit-preserving ----
    __shared__ __align__(16) float gws[NE * NE];
    {
        const float4* src = (const float4*)g_gwT;
        float4* dst = (float4*)gws;
#pragma unroll
        for (int i = 0; i < 16; ++i) {           // 4096 float4 total, 16 per thread
            dst[tid + 256 * i] = src[tid + 256 * i];
        }
    }
    __syncthreads();   // only barrier in the kernel

    float acc[NE];
#pragma unroll
    for (int f = 0; f < NE; ++f) acc[f] = 0.0f;

    // ---- logits: ascending-e fmaf chain (bit-identical to round 2) ----
    // gw rows from LDS (uniform-address broadcast ds_read_b128),
    // xe via 8-deep register rotation of coalesced global loads.
    float xr[8];
#pragma unroll
    for (int i = 0; i < 8; ++i) xr[i] = xp[(size_t)i * HW];

    for (int eg = 0; eg < 16; ++eg) {            // 16 groups of 8 channels
        float xn[8];
        if (eg < 15) {
            const float* xq = xp + (size_t)(eg + 1) * 8 * HW;
#pragma unroll
            for (int i = 0; i < 8; ++i) xn[i] = xq[(size_t)i * HW];
        }
#pragma unroll
        for (int i = 0; i < 8; ++i) {
            const float xe = xr[i];
            const float4* grow = (const float4*)&gws[(eg * 8 + i) * NE];
#pragma unroll
            for (int j = 0; j < NE / 4; ++j) {
                float4 g = grow[j];
                acc[4 * j + 0] = fmaf(g.x, xe, acc[4 * j + 0]);
                acc[4 * j + 1] = fmaf(g.y, xe, acc[4 * j + 1]);
                acc[4 * j + 2] = fmaf(g.z, xe, acc[4 * j + 2]);
                acc[4 * j + 3] = fmaf(g.w, xe, acc[4 * j + 3]);
            }
        }
        if (eg < 15) {
#pragma unroll
            for (int i = 0; i < 8; ++i) xr[i] = xn[i];
        }
    }

    // ---- + bias (zeros here; mirrored for fidelity) ----
#pragma unroll
    for (int f = 0; f < NE; ++f) acc[f] = acc[f] + gate_b[f];

    // ---- softmax, f32 numpy semantics (bit-frozen) ----
    float m = acc[0];
#pragma unroll
    for (int f = 1; f < NE; ++f) m = fmaxf(m, acc[f]);

    // correctly-rounded f32 exp of (l - m)
#pragma unroll
    for (int f = 0; f < NE; ++f) {
        acc[f] = (float)exp((double)(acc[f] - m));
    }

    // denominator: sequential ascending f32 sum (np strided-axis reduce order)
    float s = acc[0];
#pragma unroll
    for (int f = 1; f < NE; ++f) s = s + acc[f];

    // routing weights: IEEE f32 divide (ranking happens in w space -> mirror it)
#pragma unroll
    for (int f = 0; f < NE; ++f) acc[f] = acc[f] / s;

    // ---- top-8 on (w desc, idx asc): ascending-f insertion, strict '>' ----
    float t_v[NK];
    int   t_i[NK];
#pragma unroll
    for (int i = 0; i < NK; ++i) { t_v[i] = -1.0f; t_i[i] = 0; }

#pragma unroll
    for (int f = 0; f < NE; ++f) {
        float v  = acc[f];
        int   ix = f;
#pragma unroll
        for (int i = 0; i < NK; ++i) {
            bool gt = v > t_v[i];
            float tv = t_v[i]; int ti = t_i[i];
            t_v[i] = gt ? v  : tv;
            t_i[i] = gt ? ix : ti;
            v      = gt ? tv : v;
            ix     = gt ? ti : ix;
        }
    }

    // ---- gather + scale + write ----
    float* op = out + ((size_t)n * NK * HW + hw);
#pragma unroll
    for (int k = 0; k < NK; ++k) {
        float xv = xp[(size_t)t_i[k] * HW];
        op[(size_t)k * HW] = t_v[k] * xv;
    }
}

extern "C" void kernel_launch(void* const* d_in, const int* in_sizes, int n_in,
                              void* d_out, int out_size, void* d_ws, size_t ws_size,
                              hipStream_t stream) {
    // inputs: 0=x (unused), 1=experts [N,E,H,W] f32, 2=gate_w [E,E] f32, 3=gate_b [E] f32
    const float* experts = (const float*)d_in[1];
    const float* gate_w  = (const float*)d_in[2];
    const float* gate_b  = (const float*)d_in[3];
    float* out = (float*)d_out;

    hipLaunchKernelGGL(cvt_gw_kernel, dim3((NE * NE + 255) / 256), dim3(256), 0, stream, gate_w);
    hipLaunchKernelGGL(moe_kernel, dim3(NPIX / 256), dim3(256), 0, stream, experts, gate_b, out);
}

// Round 7
// 378.343 us; speedup vs baseline: 2.8713x; 1.0429x over previous
//
#include <hip/hip_runtime.h>
#include <math.h>

// Problem constants
#define NB 16      // batch
#define NE 128     // experts / channels
#define NK 8
#define HW 16384   // 128*128
#define NPIX (NB * HW)

// f32 transposed gate weights: gwT[e][f] = gate_w[f][e]
__device__ float g_gwT[NE * NE];

__global__ __launch_bounds__(256) void cvt_gw_kernel(const float* __restrict__ gate_w) {
    int i = blockIdx.x * 256 + threadIdx.x;   // i = e*128 + f
    if (i < NE * NE) {
        int e = i >> 7;
        int f = i & 127;
        g_gwT[i] = gate_w[f * NE + e];
    }
}

__global__ __launch_bounds__(256, 2) void moe_kernel(const float* __restrict__ experts,
                                                     const float* __restrict__ gate_b,
                                                     float* __restrict__ out) {
    const int tid = threadIdx.x;
    const int p   = blockIdx.x * 256 + tid;          // pixel id
    const int n   = p >> 14;                         // /16384
    const int hw  = p & (HW - 1);

    const float* xp = experts + ((size_t)n * NE * HW + hw);   // channel stride HW

    // ---- one-time stage: gwT (64 KB) into LDS, bit-preserving ----
    // +128 floats of pad so the pipeline's last lookahead read is in-bounds.
    __shared__ __align__(16) float gws[NE * NE + 128];
    {
        const float4* src = (const float4*)g_gwT;
        float4* dst = (float4*)gws;
#pragma unroll
        for (int i = 0; i < 16; ++i) {           // 4096 float4 total, 16 per thread
            dst[tid + 256 * i] = src[tid + 256 * i];
        }
    }
    __syncthreads();   // only barrier in the kernel

    float acc[NE];
#pragma unroll
    for (int f = 0; f < NE; ++f) acc[f] = 0.0f;

    // xe via 8-deep register rotation of coalesced global loads
    float xr[8], xn[8];
#pragma unroll
    for (int i = 0; i < 8; ++i) xr[i] = xp[(size_t)i * HW];

    // quarter-row double buffer: 8 float4 = 32 f-values per quarter
    float4 qb[2][8];
    {
        const float4* g0 = (const float4*)&gws[0];
#pragma unroll
        for (int j = 0; j < 8; ++j) qb[0][j] = g0[j];   // row 0, quarter 0
    }

    for (int eg = 0; eg < 16; ++eg) {            // 16 groups of 8 channels
        if (eg < 15) {                           // prefetch next x chunk
            const float* xq = xp + (size_t)(eg + 1) * 8 * HW;
#pragma unroll
            for (int i = 0; i < 8; ++i) xn[i] = xq[(size_t)i * HW];
        }
#pragma unroll
        for (int i = 0; i < 8; ++i) {
            const float xe = xr[i];
            const float4* grow = (const float4*)&gws[(eg * 8 + i) * NE];
#pragma unroll
            for (int q = 0; q < 4; ++q) {
                const int cur = q & 1;
                const int nxt = cur ^ 1;
                // preload next quarter (q==3 -> next row's quarter 0; rows are
                // contiguous in gws, last row's lookahead lands in the pad)
                const float4* gnext = (q < 3) ? (grow + 8 * (q + 1)) : (grow + 32);
#pragma unroll
                for (int j = 0; j < 8; ++j) qb[nxt][j] = gnext[j];
                // FMA current quarter: identical ascending-f fmaf chain (bit-frozen)
#pragma unroll
                for (int j = 0; j < 8; ++j) {
                    float4 g = qb[cur][j];
                    const int f0 = 32 * q + 4 * j;
                    acc[f0 + 0] = fmaf(g.x, xe, acc[f0 + 0]);
                    acc[f0 + 1] = fmaf(g.y, xe, acc[f0 + 1]);
                    acc[f0 + 2] = fmaf(g.z, xe, acc[f0 + 2]);
                    acc[f0 + 3] = fmaf(g.w, xe, acc[f0 + 3]);
                }
            }
        }
        if (eg < 15) {
#pragma unroll
            for (int i = 0; i < 8; ++i) xr[i] = xn[i];
        }
    }

    // ---- + bias (zeros here; mirrored for fidelity) ----
#pragma unroll
    for (int f = 0; f < NE; ++f) acc[f] = acc[f] + gate_b[f];

    // ---- softmax, f32 numpy semantics (bit-frozen) ----
    float m = acc[0];
#pragma unroll
    for (int f = 1; f < NE; ++f) m = fmaxf(m, acc[f]);

    // correctly-rounded f32 exp of (l - m)
#pragma unroll
    for (int f = 0; f < NE; ++f) {
        acc[f] = (float)exp((double)(acc[f] - m));
    }

    // denominator: sequential ascending f32 sum (np strided-axis reduce order)
    float s = acc[0];
#pragma unroll
    for (int f = 1; f < NE; ++f) s = s + acc[f];

    // routing weights: IEEE f32 divide (ranking happens in w space -> mirror it)
#pragma unroll
    for (int f = 0; f < NE; ++f) acc[f] = acc[f] / s;

    // ---- top-8 on (w desc, idx asc): ascending-f insertion, strict '>' ----
    float t_v[NK];
    int   t_i[NK];
#pragma unroll
    for (int i = 0; i < NK; ++i) { t_v[i] = -1.0f; t_i[i] = 0; }

#pragma unroll
    for (int f = 0; f < NE; ++f) {
        float v  = acc[f];
        int   ix = f;
#pragma unroll
        for (int i = 0; i < NK; ++i) {
            bool gt = v > t_v[i];
            float tv = t_v[i]; int ti = t_i[i];
            t_v[i] = gt ? v  : tv;
            t_i[i] = gt ? ix : ti;
            v      = gt ? tv : v;
            ix     = gt ? ti : ix;
        }
    }

    // ---- gather + scale + write ----
    float* op = out + ((size_t)n * NK * HW + hw);
#pragma unroll
    for (int k = 0; k < NK; ++k) {
        float xv = xp[(size_t)t_i[k] * HW];
        op[(size_t)k * HW] = t_v[k] * xv;
    }
}

extern "C" void kernel_launch(void* const* d_in, const int* in_sizes, int n_in,
                              void* d_out, int out_size, void* d_ws, size_t ws_size,
                              hipStream_t stream) {
    // inputs: 0=x (unused), 1=experts [N,E,H,W] f32, 2=gate_w [E,E] f32, 3=gate_b [E] f32
    const float* experts = (const float*)d_in[1];
    const float* gate_w  = (const float*)d_in[2];
    const float* gate_b  = (const float*)d_in[3];
    float* out = (float*)d_out;

    hipLaunchKernelGGL(cvt_gw_kernel, dim3((NE * NE + 255) / 256), dim3(256), 0, stream, gate_w);
    hipLaunchKernelGGL(moe_kernel, dim3(NPIX / 256), dim3(256), 0, stream, experts, gate_b, out);
}